// Round 2
// baseline (278.131 us; speedup 1.0000x reference)
//
#include <hip/hip_runtime.h>
#include <hip/hip_bf16.h>

// Fused MHA: x[8,1024,768] -> qkv -> attention -> proj. All matmuls in bf16 MFMA.
#define DIM 768
#define NH  12
#define HD  64
#define B_  8
#define N_  1024

typedef short bf16x8 __attribute__((ext_vector_type(8)));
typedef float f32x4  __attribute__((ext_vector_type(4)));

__device__ __forceinline__ ushort f2b(float x) {
  union { __hip_bfloat16 h; ushort u; } cv;
  cv.h = __float2bfloat16(x);
  return cv.u;
}

#define GLDS16(gp, lp)                                                                 \
  __builtin_amdgcn_global_load_lds((const __attribute__((address_space(1))) void*)(gp),\
                                   (__attribute__((address_space(3))) void*)(lp),      \
                                   16, 0, 0)

// ---------------- cast / transpose helpers ----------------
__global__ __launch_bounds__(256) void cast_x_kernel(const float* __restrict__ src,
                                                     ushort* __restrict__ dst, int n4) {
  int idx = blockIdx.x * 256 + threadIdx.x;
  int stride = gridDim.x * 256;
  for (int i = idx; i < n4; i += stride) {
    float4 v = reinterpret_cast<const float4*>(src)[i];
    ushort4 o;
    o.x = f2b(v.x); o.y = f2b(v.y); o.z = f2b(v.z); o.w = f2b(v.w);
    reinterpret_cast<ushort4*>(dst)[i] = o;
  }
}

// dst[C x R] = cast(src[R x C])^T
__global__ __launch_bounds__(256) void transpose_cast_kernel(const float* __restrict__ src,
                                                             ushort* __restrict__ dst,
                                                             int R, int C) {
  __shared__ float tile[32][33];
  const int tx = threadIdx.x & 31, ty = threadIdx.x >> 5;  // 8 rows per pass
  const int r0 = blockIdx.y * 32, c0 = blockIdx.x * 32;
  #pragma unroll
  for (int i = 0; i < 32; i += 8)
    tile[ty + i][tx] = src[(size_t)(r0 + ty + i) * C + c0 + tx];
  __syncthreads();
  #pragma unroll
  for (int i = 0; i < 32; i += 8)
    dst[(size_t)(c0 + ty + i) * R + r0 + tx] = f2b(tile[tx][ty + i]);
}

// ---------------- 128x128 bf16 GEMM body (A row-major [M,K], Bt row-major [N,K]) ----
// m97 structure: single LDS buffer, 2 barriers/K-step, global_load_lds w=16,
// G4 XOR swizzle (byte ^= (row&7)<<4) applied to BOTH source and ds_read.
__device__ __forceinline__ void gemm128(const ushort* __restrict__ A,
                                        const ushort* __restrict__ Bt, const int K,
                                        const int rowA0, const int rowB0,
                                        ushort* sA, ushort* sB, f32x4 acc[4][4]) {
  const int tid  = threadIdx.x;
  const int lane = tid & 63;
  const int w    = tid >> 6;
  const int wr   = w >> 1, wc = w & 1;

  int srow[4], soff[4];
  #pragma unroll
  for (int p = 0; p < 4; ++p) {
    int L   = (w * 4 + p) * 1024 + lane * 16;  // linear byte in 16KB tile
    int row = L >> 7;                          // 128 B per row (BK=64 bf16)
    int cb  = L & 127;
    srow[p] = row;
    soff[p] = cb ^ ((row & 7) << 4);           // inverse-swizzled source column
  }

  const int nk = K >> 6;
  for (int kt = 0; kt < nk; ++kt) {
    __syncthreads();  // previous compute done reading LDS
    #pragma unroll
    for (int p = 0; p < 4; ++p) {
      const char* ga = (const char*)A  + ((size_t)(rowA0 + srow[p]) * K + kt * 64) * 2 + soff[p];
      GLDS16(ga, (char*)sA + (w * 4 + p) * 1024);
      const char* gb = (const char*)Bt + ((size_t)(rowB0 + srow[p]) * K + kt * 64) * 2 + soff[p];
      GLDS16(gb, (char*)sB + (w * 4 + p) * 1024);
    }
    asm volatile("s_waitcnt vmcnt(0)" ::: "memory");
    __syncthreads();

    #pragma unroll
    for (int kk = 0; kk < 2; ++kk) {
      bf16x8 af[4], bfr[4];
      #pragma unroll
      for (int mi = 0; mi < 4; ++mi) {
        int row = wr * 64 + mi * 16 + (lane & 15);
        int cb  = kk * 64 + ((lane >> 4) << 4);
        af[mi] = *(const bf16x8*)((const char*)sA + row * 128 + (cb ^ ((row & 7) << 4)));
      }
      #pragma unroll
      for (int ni = 0; ni < 4; ++ni) {
        int row = wc * 64 + ni * 16 + (lane & 15);
        int cb  = kk * 64 + ((lane >> 4) << 4);
        bfr[ni] = *(const bf16x8*)((const char*)sB + row * 128 + (cb ^ ((row & 7) << 4)));
      }
      #pragma unroll
      for (int mi = 0; mi < 4; ++mi)
        #pragma unroll
        for (int ni = 0; ni < 4; ++ni)
          acc[mi][ni] = __builtin_amdgcn_mfma_f32_16x16x32_bf16(af[mi], bfr[ni], acc[mi][ni], 0, 0, 0);
    }
  }
}

// ---------------- QKV GEMM: C=[8192,2304], split into Q(*0.125),K:[B,H,N,64], V^T:[B,H,64,N]
__global__ __launch_bounds__(256) void qkv_gemm_kernel(const ushort* __restrict__ xb,
                                                       const ushort* __restrict__ wqkvT,
                                                       const float* __restrict__ bqkv,
                                                       ushort* __restrict__ Qb,
                                                       ushort* __restrict__ Kb,
                                                       ushort* __restrict__ Vt) {
  __shared__ ushort sA[128 * 64], sB[128 * 64];
  const int nt = blockIdx.x % 18;
  const int mt = blockIdx.x / 18;
  const int tileM = mt * 128, tileC = nt * 128;

  f32x4 acc[4][4] = {};
  gemm128(xb, wqkvT, DIM, tileM, tileC, sA, sB, acc);

  const int lane = threadIdx.x & 63, w = threadIdx.x >> 6;
  const int wr = w >> 1, wc = w & 1;
  const int s  = tileC / DIM;           // 0:Q 1:K 2:V (768 % 128 == 0 -> block-uniform)
  const int b  = tileM >> 10;
  const int n0 = (tileM & 1023) + wr * 64;
  const int h  = ((tileC % DIM) + wc * 64) >> 6;  // wave-uniform
  const int bh = b * NH + h;

  #pragma unroll
  for (int ni = 0; ni < 4; ++ni) {
    const int d = ni * 16 + (lane & 15);
    const float bias = bqkv[tileC + wc * 64 + d];
    #pragma unroll
    for (int mi = 0; mi < 4; ++mi) {
      #pragma unroll
      for (int j = 0; j < 4; ++j) {
        const int n = n0 + mi * 16 + ((lane >> 4) << 2) + j;
        const float v = acc[mi][ni][j] + bias;
        if (s == 0)      Qb[((size_t)bh * N_ + n) * HD + d] = f2b(v * 0.125f);  // fold SCALE (exact pow2)
        else if (s == 1) Kb[((size_t)bh * N_ + n) * HD + d] = f2b(v);
        else             Vt[((size_t)bh * HD + d) * N_ + n] = f2b(v);
      }
    }
  }
}

// ---------------- flash attention: one (b,h, 128 q-rows) per block, 4 independent waves
__global__ __launch_bounds__(256) void attn_kernel(const ushort* __restrict__ Qb,
                                                   const ushort* __restrict__ Kb,
                                                   const ushort* __restrict__ Vt,
                                                   ushort* __restrict__ AO) {
  __shared__ ushort P[4][32 * 72];  // per-wave P buffer, stride 72 to spread banks
  const int bh = blockIdx.x >> 3;
  const int qt = blockIdx.x & 7;
  const int lane = threadIdx.x & 63, w = threadIdx.x >> 6;
  const int q0 = qt * 128 + w * 32;
  const ushort* Qh = Qb + (size_t)bh * N_ * HD;
  const ushort* Kh = Kb + (size_t)bh * N_ * HD;
  const ushort* Vh = Vt + (size_t)bh * HD * N_;
  ushort* pb = P[w];

  // Q fragments in registers for the whole KV loop
  bf16x8 qf[2][2];
  #pragma unroll
  for (int i = 0; i < 2; ++i)
    #pragma unroll
    for (int kk = 0; kk < 2; ++kk)
      qf[i][kk] = *(const bf16x8*)&Qh[(q0 + i * 16 + (lane & 15)) * HD + kk * 32 + ((lane >> 4) << 3)];

  f32x4 oacc[2][4] = {};
  float mrun[8], ssum[8];
  #pragma unroll
  for (int im = 0; im < 8; ++im) { mrun[im] = -1e30f; ssum[im] = 0.f; }

  for (int t = 0; t < 16; ++t) {
    const int kv0 = t * 64;
    f32x4 sacc[2][4] = {};
    #pragma unroll
    for (int kk = 0; kk < 2; ++kk) {
      bf16x8 kf[4];
      #pragma unroll
      for (int nf = 0; nf < 4; ++nf)
        kf[nf] = *(const bf16x8*)&Kh[(kv0 + nf * 16 + (lane & 15)) * HD + kk * 32 + ((lane >> 4) << 3)];
      #pragma unroll
      for (int i = 0; i < 2; ++i)
        #pragma unroll
        for (int nf = 0; nf < 4; ++nf)
          sacc[i][nf] = __builtin_amdgcn_mfma_f32_16x16x32_bf16(qf[i][kk], kf[nf], sacc[i][nf], 0, 0, 0);
    }
    // online softmax; row = i*16 + (lane>>4)*4 + r, its 64 cols live in 16 lanes x 4 frags
    #pragma unroll
    for (int i = 0; i < 2; ++i) {
      #pragma unroll
      for (int r = 0; r < 4; ++r) {
        const int im = i * 4 + r;
        float tm = fmaxf(fmaxf(sacc[i][0][r], sacc[i][1][r]),
                         fmaxf(sacc[i][2][r], sacc[i][3][r]));
        #pragma unroll
        for (int d = 1; d < 16; d <<= 1) tm = fmaxf(tm, __shfl_xor(tm, d));
        const float nm   = fmaxf(mrun[im], tm);
        const float corr = __expf(mrun[im] - nm);
        mrun[im] = nm;
        float rs = 0.f;
        const int prow = (i * 16 + ((lane >> 4) << 2) + r) * 72 + (lane & 15);
        #pragma unroll
        for (int nf = 0; nf < 4; ++nf) {
          const float p = __expf(sacc[i][nf][r] - nm);
          rs += p;
          pb[prow + nf * 16] = f2b(p);
        }
        #pragma unroll
        for (int d = 1; d < 16; d <<= 1) rs += __shfl_xor(rs, d);
        ssum[im] = ssum[im] * corr + rs;
        #pragma unroll
        for (int df = 0; df < 4; ++df) oacc[i][df][r] *= corr;
      }
    }
    // PV: O += P @ V   (V^T layout makes B-fragments contiguous)
    #pragma unroll
    for (int kk = 0; kk < 2; ++kk) {
      bf16x8 pa[2], vf[4];
      #pragma unroll
      for (int i = 0; i < 2; ++i)
        pa[i] = *(const bf16x8*)&pb[(i * 16 + (lane & 15)) * 72 + kk * 32 + ((lane >> 4) << 3)];
      #pragma unroll
      for (int df = 0; df < 4; ++df)
        vf[df] = *(const bf16x8*)&Vh[(df * 16 + (lane & 15)) * N_ + kv0 + kk * 32 + ((lane >> 4) << 3)];
      #pragma unroll
      for (int i = 0; i < 2; ++i)
        #pragma unroll
        for (int df = 0; df < 4; ++df)
          oacc[i][df] = __builtin_amdgcn_mfma_f32_16x16x32_bf16(pa[i], vf[df], oacc[i][df], 0, 0, 0);
    }
  }
  // finalize: divide by softmax denom, write [8192, 768] bf16 (token-major for proj GEMM)
  const int btok = (bh / NH) * N_;
  const int hcol = (bh % NH) * HD;
  float inv[8];
  #pragma unroll
  for (int im = 0; im < 8; ++im) inv[im] = 1.f / ssum[im];
  #pragma unroll
  for (int i = 0; i < 2; ++i)
    #pragma unroll
    for (int df = 0; df < 4; ++df) {
      const int col = hcol + df * 16 + (lane & 15);
      #pragma unroll
      for (int r = 0; r < 4; ++r) {
        const int row = btok + q0 + i * 16 + ((lane >> 4) << 2) + r;
        AO[(size_t)row * DIM + col] = f2b(oacc[i][df][r] * inv[i * 4 + r]);
      }
    }
}

// ---------------- proj GEMM + bias -> fp32 out ----------------
__global__ __launch_bounds__(256) void proj_gemm_kernel(const ushort* __restrict__ AO,
                                                        const ushort* __restrict__ wprojT,
                                                        const float* __restrict__ bproj,
                                                        float* __restrict__ out) {
  __shared__ ushort sA[128 * 64], sB[128 * 64];
  const int nt = blockIdx.x % 6;
  const int mt = blockIdx.x / 6;
  f32x4 acc[4][4] = {};
  gemm128(AO, wprojT, DIM, mt * 128, nt * 128, sA, sB, acc);

  const int lane = threadIdx.x & 63, w = threadIdx.x >> 6;
  const int wr = w >> 1, wc = w & 1;
  #pragma unroll
  for (int ni = 0; ni < 4; ++ni) {
    const int col = nt * 128 + wc * 64 + ni * 16 + (lane & 15);
    const float bias = bproj[col];
    #pragma unroll
    for (int mi = 0; mi < 4; ++mi) {
      const int row = mt * 128 + wr * 64 + mi * 16 + ((lane >> 4) << 2);
      #pragma unroll
      for (int j = 0; j < 4; ++j)
        out[(size_t)(row + j) * DIM + col] = acc[mi][ni][j] + bias;
    }
  }
}

extern "C" void kernel_launch(void* const* d_in, const int* in_sizes, int n_in,
                              void* d_out, int out_size, void* d_ws, size_t ws_size,
                              hipStream_t stream) {
  const float* x      = (const float*)d_in[0];
  const float* w_qkv  = (const float*)d_in[1];
  const float* b_qkv  = (const float*)d_in[2];
  const float* w_proj = (const float*)d_in[3];
  const float* b_proj = (const float*)d_in[4];
  float* out = (float*)d_out;

  // workspace layout (ushort elements), total ~67.6 MB
  ushort* xb     = (ushort*)d_ws;        // 8192*768
  ushort* wqkvT  = xb + 6291456;         // 2304*768
  ushort* wprojT = wqkvT + 1769472;      // 768*768
  ushort* Qb     = wprojT + 589824;      // [B,H,N,64]
  ushort* Kb     = Qb + 6291456;         // [B,H,N,64]
  ushort* Vt     = Kb + 6291456;         // [B,H,64,N]
  ushort* AO     = Vt + 6291456;         // [8192,768]
  (void)in_sizes; (void)n_in; (void)out_size; (void)ws_size;

  cast_x_kernel<<<2048, 256, 0, stream>>>(x, xb, 6291456 / 4);
  transpose_cast_kernel<<<dim3(2304 / 32, 768 / 32), 256, 0, stream>>>(w_qkv, wqkvT, DIM, 3 * DIM);
  transpose_cast_kernel<<<dim3(768 / 32, 768 / 32), 256, 0, stream>>>(w_proj, wprojT, DIM, DIM);
  qkv_gemm_kernel<<<64 * 18, 256, 0, stream>>>(xb, wqkvT, b_qkv, Qb, Kb, Vt);
  attn_kernel<<<96 * 8, 256, 0, stream>>>(Qb, Kb, Vt, AO);
  proj_gemm_kernel<<<64 * 6, 256, 0, stream>>>(AO, wprojT, b_proj, out);
}